// Round 1
// baseline (504.607 us; speedup 1.0000x reference)
//
#include <hip/hip_runtime.h>
#include <math.h>

#define B 128
#define M 32
#define P 8732
#define C 21
#define ALPHA 10.0f
#define TPB2 256
#define PPB 256          // priors per block in fused kernel (1 per lane, 64 per wave)
#define NB2 35           // ceil(P / PPB)
#define CH 8             // k1 prior chunks
#define CS 1092          // ceil(P / CH)

// direct global->LDS DMA, 16 B/lane, wave-uniform LDS base + lane*16 scatter
#define GLD16(g, l)                                                   \
  __builtin_amdgcn_global_load_lds(                                   \
      (__attribute__((address_space(1))) void*)(g),                   \
      (__attribute__((address_space(3))) void*)(l), 16, 0, 0)

// ---------------- k1a: per-chunk best prior per object (partials) -----------
__global__ __launch_bounds__(256) void k1_partial(
    const float* __restrict__ b_boxes, const float* __restrict__ priors,
    float* __restrict__ pI, float* __restrict__ pU, int* __restrict__ pidx,
    int* __restrict__ done, int* __restrict__ imgcnt) {
  if (blockIdx.x == 0) {
    if (threadIdx.x == 0) *done = 0;
    if (threadIdx.x < B) imgcnt[threadIdx.x] = 0;  // per-image block counters
  }
  int b = blockIdx.x >> 3;
  int ch = blockIdx.x & 7;
  int wid = threadIdx.x >> 6;
  int lane = threadIdx.x & 63;
  int obase = wid * 8;

  float ox1[8], oy1[8], ox2[8], oy2[8], oarea[8], bI[8], bU[8];
  int bidx[8];
#pragma unroll
  for (int k = 0; k < 8; k++) {
    float4 bx = ((const float4*)b_boxes)[(size_t)b * M + obase + k];
    ox1[k] = bx.x; oy1[k] = bx.y; ox2[k] = bx.z; oy2[k] = bx.w;
    oarea[k] = (bx.z - bx.x) * (bx.w - bx.y);
    bI[k] = -1.0f; bU[k] = 1.0f; bidx[k] = P;
  }

  int pend = (ch + 1) * CS;
  if (pend > P) pend = P;
#pragma unroll 2
  for (int p = ch * CS + lane; p < pend; p += 64) {
    float4 pr = ((const float4*)priors)[p];
    float pw2 = pr.z * 0.5f, ph2 = pr.w * 0.5f;
    float px1 = pr.x - pw2, py1 = pr.y - ph2;
    float px2 = pr.x + pw2, py2 = pr.y + ph2;
    float areaP = pr.z * pr.w;
#pragma unroll
    for (int k = 0; k < 8; k++) {
      float iw = fminf(ox2[k], px2) - fmaxf(ox1[k], px1);
      float ih = fminf(oy2[k], py2) - fmaxf(oy1[k], py1);
      iw = fmaxf(iw, 0.0f);
      ih = fmaxf(ih, 0.0f);
      float inter = iw * ih;
      float uni = oarea[k] + areaP - inter;
      if (inter * bU[k] > bI[k] * uni) { bI[k] = inter; bU[k] = uni; bidx[k] = p; }
    }
  }
  for (int off = 32; off >= 1; off >>= 1) {
#pragma unroll
    for (int k = 0; k < 8; k++) {
      float oI = __shfl_xor(bI[k], off, 64);
      float oU = __shfl_xor(bU[k], off, 64);
      int oi = __shfl_xor(bidx[k], off, 64);
      float l = oI * bU[k], r = bI[k] * oU;
      if (l > r || (l == r && oi < bidx[k])) { bI[k] = oI; bU[k] = oU; bidx[k] = oi; }
    }
  }
  if (lane == 0) {
#pragma unroll
    for (int k = 0; k < 8; k++) {
      int idx = ((size_t)b * M + obase + k) * CH + ch;
      pI[idx] = bI[k]; pU[idx] = bU[k]; pidx[idx] = bidx[k];
    }
  }
}

// ---------------- fused k2+k3: per-prior match + CE, then per-image ---------
// hard-negative top-K done by the LAST block of each image (done-counter
// pattern), overlapping select tails with other images' CE work. confneg is
// re-read from L2/L3, not LDS-staged, so phase-A occupancy stays 6 blk/CU.
__global__ __launch_bounds__(TPB2) void k23_fused(
    const float* __restrict__ pred_loc, const float* __restrict__ pred_cls,
    const float* __restrict__ b_boxes, const int* __restrict__ b_labels,
    const float* __restrict__ priors,
    const float* __restrict__ pI, const float* __restrict__ pU,
    const int* __restrict__ pidx,
    float* __restrict__ ploc, float* __restrict__ pce, int* __restrict__ pnp,
    float* __restrict__ confneg, int* __restrict__ imgcnt,
    float* __restrict__ imgres, int* __restrict__ done,
    float* __restrict__ out) {
  int b = blockIdx.y;
  int p0 = blockIdx.x * PPB;
  int tid = threadIdx.x;
  int wid = tid >> 6;
  int lane = tid & 63;

  __shared__ __align__(16) union SU {
    struct {
      float cls[4][64 * C];  // 21504 B (wave-private class tiles)
      float4 box[M];
      float area[M];
      int lab[M];
      int obj[M];
      int inv[PPB];
    } a;
    struct {               // phase B (select) scratch — reuses phase-A LDS
      int histw[4 * 256];  // per-wave radix histograms
      int cnt[256];
      float rsum[4];
      int rcnt[4];
      float rl[4], rc[4], rh[4], rn[4];
    } s3;
  } u;
  __shared__ float rloc[4], rce[4];
  __shared__ int rnp[4];
  __shared__ int sdig, scum, sLastBlk, sLastImg, sK;
  __shared__ float sLoc, sCe, sNp;

  // ---------------- phase A: identical to previous k2 -----------------------
  // issue the DMA staging FIRST so it overlaps the setup work below
  {
    int wp0 = p0 + wid * 64;
    int nv = P - wp0;
    nv = nv < 0 ? 0 : (nv > 64 ? 64 : nv);
    int nf4 = (nv * C) >> 2;  // 336 (full), 147 (tail), or 0
    const float4* src = (const float4*)(pred_cls + ((size_t)b * P + wp0) * C);
#pragma unroll
    for (int k = 0; k < 6; k++) {
      int idx = (k << 6) + lane;
      if (idx < nf4) GLD16(src + idx, &u.a.cls[wid][k << 8]);
    }
  }

  u.a.inv[tid] = 0x7fffffff;
  if (tid < M) {
    int m = tid;
    float4 bx = ((const float4*)b_boxes)[b * M + m];
    u.a.box[m] = bx;
    u.a.area[m] = (bx.z - bx.x) * (bx.w - bx.y);
    u.a.lab[m] = b_labels[b * M + m];
    // fused k1_reduce: fold 8 chunk partials for object m of image b
    int o = b * M + m;
    float cI = pI[o * CH], cU = pU[o * CH];
    int ci = pidx[o * CH];
#pragma unroll
    for (int ch = 1; ch < CH; ch++) {
      float nI = pI[o * CH + ch], nU = pU[o * CH + ch];
      int ni = pidx[o * CH + ch];
      if (nI * cU > cI * nU) { cI = nI; cU = nU; ci = ni; }
    }
    u.a.obj[m] = ci;
  }
  __syncthreads();
  if (tid < M) {
    int t = u.a.obj[tid] - p0;
    if (t >= 0 && t < PPB) atomicMin(&u.a.inv[t], tid);
  }
  __syncthreads();  // drains the global_load_lds vmcnt + orders inv

  float locpart = 0.0f, cepospart = 0.0f;
  int npos = 0;
  int p = p0 + tid;
  if (p < P) {
    float4 pr = ((const float4*)priors)[p];
    float pw2 = pr.z * 0.5f, ph2 = pr.w * 0.5f;
    float px1 = pr.x - pw2, py1 = pr.y - ph2;
    float px2 = pr.x + pw2, py2 = pr.y + ph2;
    float areaP = pr.z * pr.w;
    float bI = -1.0f, bU = 1.0f;
    int bm = 0;
    for (int m = 0; m < M; m++) {
      float4 bx = u.a.box[m];  // one ds_read_b128 broadcast per object
      float iw = fminf(bx.z, px2) - fmaxf(bx.x, px1);
      float ih = fminf(bx.w, py2) - fmaxf(bx.y, py1);
      iw = fmaxf(iw, 0.0f);
      ih = fmaxf(ih, 0.0f);
      float inter = iw * ih;
      float uni = u.a.area[m] + areaP - inter;
      if (inter * bU > bI * uni) { bI = inter; bU = uni; bm = m; }
    }
    // forced best-prior override (first-max semantics preserved)
    int fm = u.a.inv[tid];
    if (fm != 0x7fffffff) {
      if (!((bI == bU) && (bm < fm))) { bI = 1.0f; bU = 1.0f; bm = fm; }
    }
    bool pos = (2.0f * bI >= bU);  // iou >= 0.5, division-free
    int wAny = __any((int)pos);

    if (wAny) {  // wave-uniform positive path: loc load + encode + L1 loss
      float4 pl = ((const float4*)pred_loc)[(size_t)b * P + p];
      float4 bx = u.a.box[bm];
      float cx = (bx.x + bx.z) * 0.5f, cy = (bx.y + bx.w) * 0.5f;
      float w = bx.z - bx.x, h = bx.w - bx.y;
      float rz = __builtin_amdgcn_rcpf(pr.z);
      float rw = __builtin_amdgcn_rcpf(pr.w);
      float g0 = (cx - pr.x) * 10.0f * rz;
      float g1 = (cy - pr.y) * 10.0f * rw;
      float g2 = __logf(w * rz) * 5.0f;
      float g3 = __logf(h * rw) * 5.0f;
      if (pos) {
        locpart = fabsf(pl.x - g0) + fabsf(pl.y - g1) +
                  fabsf(pl.z - g2) + fabsf(pl.w - g3);
        npos = 1;
      }
    }

    // CE from LDS (unstabilized logsumexp; verified absmax 0.0 since R9)
    const float* cptr = &u.a.cls[wid][lane * C];
    int cls = pos ? u.a.lab[bm] : 0;
    float se = 0.0f, vc = 0.0f;
#pragma unroll
    for (int c = 0; c < C; c++) {
      float x = cptr[c];
      se += __expf(x);
      if (c == cls) vc = x;  // predicated select, constant index
    }
    float ce = __logf(se) - vc;
    confneg[(size_t)b * P + p] = pos ? 0.0f : ce;
    cepospart = pos ? ce : 0.0f;
  }

  for (int off = 32; off >= 1; off >>= 1) {
    locpart += __shfl_down(locpart, off, 64);
    cepospart += __shfl_down(cepospart, off, 64);
    npos += __shfl_down(npos, off, 64);
  }
  if (lane == 0) { rloc[wid] = locpart; rce[wid] = cepospart; rnp[wid] = npos; }
  __syncthreads();
  if (tid == 0) {
    int f = b * NB2 + blockIdx.x;
    ploc[f] = rloc[0] + rloc[1] + rloc[2] + rloc[3];
    pce[f] = rce[0] + rce[1] + rce[2] + rce[3];
    pnp[f] = rnp[0] + rnp[1] + rnp[2] + rnp[3];
    __threadfence();                        // release partials + confneg row
    int prev = atomicAdd(&imgcnt[b], 1);
    sLastBlk = (prev == NB2 - 1) ? 1 : 0;
  }
  __syncthreads();
  if (!sLastBlk) return;
  __threadfence();  // acquire: other blocks' confneg + partials now visible

  // ---------------- phase B: this image's hard-negative top-K ---------------
  if (wid == 0) {  // reduce this image's 35 per-block partials
    float lp = 0.0f, cp = 0.0f;
    int np = 0;
    if (lane < NB2) {
      int f = b * NB2 + lane;
      lp = ploc[f]; cp = pce[f]; np = pnp[f];
    }
    for (int off = 32; off >= 1; off >>= 1) {
      lp += __shfl_down(lp, off, 64);
      cp += __shfl_down(cp, off, 64);
      np += __shfl_down(np, off, 64);
    }
    if (lane == 0) {
      int K = np * 3;
      if (K > P) K = P;
      sK = K; sLoc = lp; sCe = cp; sNp = (float)np;
    }
  }
  __syncthreads();

  const float4* row4 = (const float4*)(confneg + (size_t)b * P);  // P/4 = 2183
  int K = sK;
  unsigned pfx = 0;
  int Krem = K;
#pragma unroll
  for (int pass = 3; pass >= 0; --pass) {
    int sh = pass * 8;
    for (int i = tid; i < 4 * 256; i += TPB2) u.s3.histw[i] = 0;
    __syncthreads();
    unsigned himask = (pass == 3) ? 0u : (0xFFFFFFFFu << (sh + 8));
    int* myh = &u.s3.histw[wid * 256];
    for (int i = tid; i < P / 4; i += TPB2) {
      float4 v = row4[i];  // L2/L3-resident (written moments ago)
      unsigned u0 = __float_as_uint(v.x), u1 = __float_as_uint(v.y);
      unsigned u2 = __float_as_uint(v.z), u3 = __float_as_uint(v.w);
      if ((u0 & himask) == pfx) atomicAdd(&myh[(u0 >> sh) & 255], 1);
      if ((u1 & himask) == pfx) atomicAdd(&myh[(u1 >> sh) & 255], 1);
      if ((u2 & himask) == pfx) atomicAdd(&myh[(u2 >> sh) & 255], 1);
      if ((u3 & himask) == pfx) atomicAdd(&myh[(u3 >> sh) & 255], 1);
    }
    __syncthreads();
    {
      int c = u.s3.histw[tid] + u.s3.histw[256 + tid] +
              u.s3.histw[512 + tid] + u.s3.histw[768 + tid];
      u.s3.cnt[tid] = c;
    }
    __syncthreads();
    if (wid == 0) {
      int4 c4 = ((const int4*)u.s3.cnt)[lane];
      int s3v = c4.w;
      int s2 = c4.z + s3v;
      int s1 = c4.y + s2;
      int s0 = c4.x + s1;
      int suf = s0;
      for (int off = 1; off < 64; off <<= 1) {
        int t = __shfl_down(suf, off, 64);
        if (lane + off < 64) suf += t;
      }
      int above = suf - s0;
      int S0 = above + s0, S1 = above + s1, S2 = above + s2, S3 = above + s3v;
      int S4 = above;
      if (S3 >= Krem && S4 < Krem) { sdig = 4 * lane + 3; scum = S4; }
      else if (S2 >= Krem && S3 < Krem) { sdig = 4 * lane + 2; scum = S3; }
      else if (S1 >= Krem && S2 < Krem) { sdig = 4 * lane + 1; scum = S2; }
      else if (S0 >= Krem && S1 < Krem) { sdig = 4 * lane + 0; scum = S1; }
    }
    __syncthreads();
    pfx |= ((unsigned)sdig) << sh;
    Krem -= scum;
  }
  float tau = __uint_as_float(pfx);

  float sum = 0.0f;
  int cgt = 0;
  for (int i = tid; i < P / 4; i += TPB2) {
    float4 v = row4[i];
    if (v.x > tau) { sum += v.x; cgt++; }
    if (v.y > tau) { sum += v.y; cgt++; }
    if (v.z > tau) { sum += v.z; cgt++; }
    if (v.w > tau) { sum += v.w; cgt++; }
  }
  for (int off = 32; off >= 1; off >>= 1) {
    sum += __shfl_down(sum, off, 64);
    cgt += __shfl_down(cgt, off, 64);
  }
  if (lane == 0) { u.s3.rsum[wid] = sum; u.s3.rcnt[wid] = cgt; }
  __syncthreads();
  if (tid == 0) {
    float stot = u.s3.rsum[0] + u.s3.rsum[1] + u.s3.rsum[2] + u.s3.rsum[3];
    int ctot = u.s3.rcnt[0] + u.s3.rcnt[1] + u.s3.rcnt[2] + u.s3.rcnt[3];
    float hard = stot + (float)(K - ctot) * tau;
    imgres[b * 4 + 0] = sLoc;
    imgres[b * 4 + 1] = sCe;
    imgres[b * 4 + 2] = hard;
    imgres[b * 4 + 3] = sNp;
    __threadfence();
    int prev = atomicAdd(done, 1);
    sLastImg = (prev == B - 1) ? 1 : 0;
  }
  __syncthreads();
  if (sLastImg) {
    __threadfence();
    float l = 0.0f, c = 0.0f, h = 0.0f, n = 0.0f;
    if (tid < B) {
      l = atomicAdd(&imgres[tid * 4 + 0], 0.0f);
      c = atomicAdd(&imgres[tid * 4 + 1], 0.0f);
      h = atomicAdd(&imgres[tid * 4 + 2], 0.0f);
      n = atomicAdd(&imgres[tid * 4 + 3], 0.0f);
    }
    for (int off = 32; off >= 1; off >>= 1) {
      l += __shfl_down(l, off, 64);
      c += __shfl_down(c, off, 64);
      h += __shfl_down(h, off, 64);
      n += __shfl_down(n, off, 64);
    }
    if (lane == 0) { u.s3.rl[wid] = l; u.s3.rc[wid] = c; u.s3.rh[wid] = h; u.s3.rn[wid] = n; }
    __syncthreads();
    if (tid == 0) {
      float L = 0, Cc = 0, H = 0, N = 0;
#pragma unroll
      for (int w = 0; w < 4; w++) {
        L += u.s3.rl[w]; Cc += u.s3.rc[w]; H += u.s3.rh[w]; N += u.s3.rn[w];
      }
      float loc = ALPHA * L / (N * 4.0f);
      float conf = (H + Cc) / N;
      out[0] = conf + loc;
      out[1] = loc;
      out[2] = conf;
    }
  }
}

extern "C" void kernel_launch(void* const* d_in, const int* in_sizes, int n_in,
                              void* d_out, int out_size, void* d_ws, size_t ws_size,
                              hipStream_t stream) {
  (void)in_sizes; (void)n_in; (void)out_size; (void)ws_size;
  const float* pred_loc = (const float*)d_in[0];
  const float* pred_cls = (const float*)d_in[1];
  const float* b_boxes = (const float*)d_in[2];
  const int* b_labels = (const int*)d_in[3];
  const float* priors = (const float*)d_in[4];
  float* out = (float*)d_out;

  int* done = (int*)d_ws;
  int* imgcnt = (int*)d_ws + 8;
  float* ploc = (float*)d_ws + 8 + B;
  float* pce = ploc + B * NB2;
  int* pnp = (int*)(pce + B * NB2);
  float* imgres = (float*)(pnp + B * NB2);
  float* pI = imgres + B * 4;
  float* pU = pI + B * M * CH;
  int* pidx = (int*)(pU + B * M * CH);
  float* confneg = (float*)(pidx + B * M * CH);  // 16B-aligned (offset 449568)

  k1_partial<<<B * CH, 256, 0, stream>>>(b_boxes, priors, pI, pU, pidx, done, imgcnt);
  dim3 g2(NB2, B);
  k23_fused<<<g2, TPB2, 0, stream>>>(pred_loc, pred_cls, b_boxes, b_labels,
                                     priors, pI, pU, pidx, ploc, pce, pnp,
                                     confneg, imgcnt, imgres, done, out);
}

// Round 3
// 277.435 us; speedup vs baseline: 1.8188x; 1.8188x over previous
//
#include <hip/hip_runtime.h>
#include <math.h>

#define B 128
#define M 32
#define P 8732
#define C 21
#define ALPHA 10.0f
#define TPB2 256
#define PPB 256          // priors per block in fused kernel (1 per lane, 64 per wave)
#define NB2 35           // ceil(P / PPB)
#define CH 8             // k1 prior chunks
#define CS 1092          // ceil(P / CH)

// direct global->LDS DMA, 16 B/lane, wave-uniform LDS base + lane*16 scatter
#define GLD16(g, l)                                                   \
  __builtin_amdgcn_global_load_lds(                                   \
      (__attribute__((address_space(1))) void*)(g),                   \
      (__attribute__((address_space(3))) void*)(l), 16, 0, 0)

// agent-scope relaxed store: lowers to an sc1 write that reaches the MALL
// (cross-XCD coherence point) without any buffer_wbl2 L2 flush.
#define ST_AGENT(p, v) \
  __hip_atomic_store((p), (v), __ATOMIC_RELAXED, __HIP_MEMORY_SCOPE_AGENT)

// ---------------- k1a: per-chunk best prior per object (partials) -----------
__global__ __launch_bounds__(256) void k1_partial(
    const float* __restrict__ b_boxes, const float* __restrict__ priors,
    float* __restrict__ pI, float* __restrict__ pU, int* __restrict__ pidx,
    int* __restrict__ done, int* __restrict__ imgcnt) {
  if (blockIdx.x == 0) {
    if (threadIdx.x == 0) *done = 0;
    if (threadIdx.x < B) imgcnt[threadIdx.x] = 0;  // per-image block counters
  }
  int b = blockIdx.x >> 3;
  int ch = blockIdx.x & 7;
  int wid = threadIdx.x >> 6;
  int lane = threadIdx.x & 63;
  int obase = wid * 8;

  float ox1[8], oy1[8], ox2[8], oy2[8], oarea[8], bI[8], bU[8];
  int bidx[8];
#pragma unroll
  for (int k = 0; k < 8; k++) {
    float4 bx = ((const float4*)b_boxes)[(size_t)b * M + obase + k];
    ox1[k] = bx.x; oy1[k] = bx.y; ox2[k] = bx.z; oy2[k] = bx.w;
    oarea[k] = (bx.z - bx.x) * (bx.w - bx.y);
    bI[k] = -1.0f; bU[k] = 1.0f; bidx[k] = P;
  }

  int pend = (ch + 1) * CS;
  if (pend > P) pend = P;
#pragma unroll 2
  for (int p = ch * CS + lane; p < pend; p += 64) {
    float4 pr = ((const float4*)priors)[p];
    float pw2 = pr.z * 0.5f, ph2 = pr.w * 0.5f;
    float px1 = pr.x - pw2, py1 = pr.y - ph2;
    float px2 = pr.x + pw2, py2 = pr.y + ph2;
    float areaP = pr.z * pr.w;
#pragma unroll
    for (int k = 0; k < 8; k++) {
      float iw = fminf(ox2[k], px2) - fmaxf(ox1[k], px1);
      float ih = fminf(oy2[k], py2) - fmaxf(oy1[k], py1);
      iw = fmaxf(iw, 0.0f);
      ih = fmaxf(ih, 0.0f);
      float inter = iw * ih;
      float uni = oarea[k] + areaP - inter;
      if (inter * bU[k] > bI[k] * uni) { bI[k] = inter; bU[k] = uni; bidx[k] = p; }
    }
  }
  for (int off = 32; off >= 1; off >>= 1) {
#pragma unroll
    for (int k = 0; k < 8; k++) {
      float oI = __shfl_xor(bI[k], off, 64);
      float oU = __shfl_xor(bU[k], off, 64);
      int oi = __shfl_xor(bidx[k], off, 64);
      float l = oI * bU[k], r = bI[k] * oU;
      if (l > r || (l == r && oi < bidx[k])) { bI[k] = oI; bU[k] = oU; bidx[k] = oi; }
    }
  }
  if (lane == 0) {
#pragma unroll
    for (int k = 0; k < 8; k++) {
      int idx = ((size_t)b * M + obase + k) * CH + ch;
      pI[idx] = bI[k]; pU[idx] = bU[k]; pidx[idx] = bidx[k];
    }
  }
}

// ---------------- fused k2+k3: per-prior match + CE, then per-image ---------
// hard-negative top-K done by the LAST block of each image (done-counter
// pattern). Cross-XCD handoff uses sc1 (agent-scope relaxed) stores +
// vmcnt drain + relaxed atomics; reader does an acquire-only buffer_inv.
// NO buffer_wbl2 (that was the 325 us regression in the previous round).
__global__ __launch_bounds__(TPB2) void k23_fused(
    const float* __restrict__ pred_loc, const float* __restrict__ pred_cls,
    const float* __restrict__ b_boxes, const int* __restrict__ b_labels,
    const float* __restrict__ priors,
    const float* __restrict__ pI, const float* __restrict__ pU,
    const int* __restrict__ pidx,
    float* __restrict__ ploc, float* __restrict__ pce, int* __restrict__ pnp,
    float* __restrict__ confneg, int* __restrict__ imgcnt,
    float* __restrict__ imgres, int* __restrict__ done,
    float* __restrict__ out) {
  int b = blockIdx.y;
  int p0 = blockIdx.x * PPB;
  int tid = threadIdx.x;
  int wid = tid >> 6;
  int lane = tid & 63;

  __shared__ __align__(16) union SU {
    struct {
      float cls[4][64 * C];  // 21504 B (wave-private class tiles)
      float4 box[M];
      float area[M];
      int lab[M];
      int obj[M];
      int inv[PPB];
    } a;
    struct {               // phase B (select) scratch — reuses phase-A LDS
      int histw[4 * 256];  // per-wave radix histograms
      int cnt[256];
      float rsum[4];
      int rcnt[4];
      float rl[4], rc[4], rh[4], rn[4];
    } s3;
  } u;
  __shared__ float rloc[4], rce[4];
  __shared__ int rnp[4];
  __shared__ int sdig, scum, sLastBlk, sLastImg, sK;
  __shared__ float sLoc, sCe, sNp;

  // ---------------- phase A: identical structure to the 214us k2 ------------
  {
    int wp0 = p0 + wid * 64;
    int nv = P - wp0;
    nv = nv < 0 ? 0 : (nv > 64 ? 64 : nv);
    int nf4 = (nv * C) >> 2;  // 336 (full), 147 (tail), or 0
    const float4* src = (const float4*)(pred_cls + ((size_t)b * P + wp0) * C);
#pragma unroll
    for (int k = 0; k < 6; k++) {
      int idx = (k << 6) + lane;
      if (idx < nf4) GLD16(src + idx, &u.a.cls[wid][k << 8]);
    }
  }

  u.a.inv[tid] = 0x7fffffff;
  if (tid < M) {
    int m = tid;
    float4 bx = ((const float4*)b_boxes)[b * M + m];
    u.a.box[m] = bx;
    u.a.area[m] = (bx.z - bx.x) * (bx.w - bx.y);
    u.a.lab[m] = b_labels[b * M + m];
    // fused k1_reduce: fold 8 chunk partials for object m of image b
    int o = b * M + m;
    float cI = pI[o * CH], cU = pU[o * CH];
    int ci = pidx[o * CH];
#pragma unroll
    for (int ch = 1; ch < CH; ch++) {
      float nI = pI[o * CH + ch], nU = pU[o * CH + ch];
      int ni = pidx[o * CH + ch];
      if (nI * cU > cI * nU) { cI = nI; cU = nU; ci = ni; }
    }
    u.a.obj[m] = ci;
  }
  __syncthreads();
  if (tid < M) {
    int t = u.a.obj[tid] - p0;
    if (t >= 0 && t < PPB) atomicMin(&u.a.inv[t], tid);
  }
  __syncthreads();  // drains the global_load_lds vmcnt + orders inv

  float locpart = 0.0f, cepospart = 0.0f;
  int npos = 0;
  int p = p0 + tid;
  if (p < P) {
    float4 pr = ((const float4*)priors)[p];
    float pw2 = pr.z * 0.5f, ph2 = pr.w * 0.5f;
    float px1 = pr.x - pw2, py1 = pr.y - ph2;
    float px2 = pr.x + pw2, py2 = pr.y + ph2;
    float areaP = pr.z * pr.w;
    float bI = -1.0f, bU = 1.0f;
    int bm = 0;
    for (int m = 0; m < M; m++) {
      float4 bx = u.a.box[m];  // one ds_read_b128 broadcast per object
      float iw = fminf(bx.z, px2) - fmaxf(bx.x, px1);
      float ih = fminf(bx.w, py2) - fmaxf(bx.y, py1);
      iw = fmaxf(iw, 0.0f);
      ih = fmaxf(ih, 0.0f);
      float inter = iw * ih;
      float uni = u.a.area[m] + areaP - inter;
      if (inter * bU > bI * uni) { bI = inter; bU = uni; bm = m; }
    }
    // forced best-prior override (first-max semantics preserved)
    int fm = u.a.inv[tid];
    if (fm != 0x7fffffff) {
      if (!((bI == bU) && (bm < fm))) { bI = 1.0f; bU = 1.0f; bm = fm; }
    }
    bool pos = (2.0f * bI >= bU);  // iou >= 0.5, division-free
    int wAny = __any((int)pos);

    if (wAny) {  // wave-uniform positive path: loc load + encode + L1 loss
      float4 pl = ((const float4*)pred_loc)[(size_t)b * P + p];
      float4 bx = u.a.box[bm];
      float cx = (bx.x + bx.z) * 0.5f, cy = (bx.y + bx.w) * 0.5f;
      float w = bx.z - bx.x, h = bx.w - bx.y;
      float rz = __builtin_amdgcn_rcpf(pr.z);
      float rw = __builtin_amdgcn_rcpf(pr.w);
      float g0 = (cx - pr.x) * 10.0f * rz;
      float g1 = (cy - pr.y) * 10.0f * rw;
      float g2 = __logf(w * rz) * 5.0f;
      float g3 = __logf(h * rw) * 5.0f;
      if (pos) {
        locpart = fabsf(pl.x - g0) + fabsf(pl.y - g1) +
                  fabsf(pl.z - g2) + fabsf(pl.w - g3);
        npos = 1;
      }
    }

    // CE from LDS (unstabilized logsumexp; verified absmax 0.0 since R9)
    const float* cptr = &u.a.cls[wid][lane * C];
    int cls = pos ? u.a.lab[bm] : 0;
    float se = 0.0f, vc = 0.0f;
#pragma unroll
    for (int c = 0; c < C; c++) {
      float x = cptr[c];
      se += __expf(x);
      if (c == cls) vc = x;  // predicated select, constant index
    }
    float ce = __logf(se) - vc;
    ST_AGENT(&confneg[(size_t)b * P + p], pos ? 0.0f : ce);  // sc1: reaches L3
    cepospart = pos ? ce : 0.0f;
  }

  for (int off = 32; off >= 1; off >>= 1) {
    locpart += __shfl_down(locpart, off, 64);
    cepospart += __shfl_down(cepospart, off, 64);
    npos += __shfl_down(npos, off, 64);
  }
  if (lane == 0) { rloc[wid] = locpart; rce[wid] = cepospart; rnp[wid] = npos; }
  // every wave drains its own sc1 confneg stores to the coherence point
  asm volatile("s_waitcnt vmcnt(0)" ::: "memory");
  __syncthreads();
  if (tid == 0) {
    int f = b * NB2 + blockIdx.x;
    ST_AGENT(&ploc[f], rloc[0] + rloc[1] + rloc[2] + rloc[3]);
    ST_AGENT(&pce[f], rce[0] + rce[1] + rce[2] + rce[3]);
    ST_AGENT(&pnp[f], rnp[0] + rnp[1] + rnp[2] + rnp[3]);
    asm volatile("s_waitcnt vmcnt(0)" ::: "memory");  // partials at L3
    int prev = __hip_atomic_fetch_add(&imgcnt[b], 1, __ATOMIC_RELAXED,
                                      __HIP_MEMORY_SCOPE_AGENT);
    sLastBlk = (prev == NB2 - 1) ? 1 : 0;
  }
  __syncthreads();
  if (!sLastBlk) return;
  // acquire-only: buffer_inv (L1+L2 invalidate), NO writeback
  __builtin_amdgcn_fence(__ATOMIC_ACQUIRE, "agent");

  // ---------------- phase B: this image's hard-negative top-K ---------------
  if (wid == 0) {  // reduce this image's 35 per-block partials
    float lp = 0.0f, cp = 0.0f;
    int np = 0;
    if (lane < NB2) {
      int f = b * NB2 + lane;
      lp = ploc[f]; cp = pce[f]; np = pnp[f];
    }
    for (int off = 32; off >= 1; off >>= 1) {
      lp += __shfl_down(lp, off, 64);
      cp += __shfl_down(cp, off, 64);
      np += __shfl_down(np, off, 64);
    }
    if (lane == 0) {
      int K = np * 3;
      if (K > P) K = P;
      sK = K; sLoc = lp; sCe = cp; sNp = (float)np;
    }
  }
  __syncthreads();

  const float4* row4 = (const float4*)(confneg + (size_t)b * P);  // P/4 = 2183
  int K = sK;
  unsigned pfx = 0;
  int Krem = K;
#pragma unroll
  for (int pass = 3; pass >= 0; --pass) {
    int sh = pass * 8;
    for (int i = tid; i < 4 * 256; i += TPB2) u.s3.histw[i] = 0;
    __syncthreads();
    unsigned himask = (pass == 3) ? 0u : (0xFFFFFFFFu << (sh + 8));
    int* myh = &u.s3.histw[wid * 256];
    for (int i = tid; i < P / 4; i += TPB2) {
      float4 v = row4[i];  // L3-resident (written through moments ago)
      unsigned u0 = __float_as_uint(v.x), u1 = __float_as_uint(v.y);
      unsigned u2 = __float_as_uint(v.z), u3 = __float_as_uint(v.w);
      if ((u0 & himask) == pfx) atomicAdd(&myh[(u0 >> sh) & 255], 1);
      if ((u1 & himask) == pfx) atomicAdd(&myh[(u1 >> sh) & 255], 1);
      if ((u2 & himask) == pfx) atomicAdd(&myh[(u2 >> sh) & 255], 1);
      if ((u3 & himask) == pfx) atomicAdd(&myh[(u3 >> sh) & 255], 1);
    }
    __syncthreads();
    {
      int c = u.s3.histw[tid] + u.s3.histw[256 + tid] +
              u.s3.histw[512 + tid] + u.s3.histw[768 + tid];
      u.s3.cnt[tid] = c;
    }
    __syncthreads();
    if (wid == 0) {
      int4 c4 = ((const int4*)u.s3.cnt)[lane];
      int s3v = c4.w;
      int s2 = c4.z + s3v;
      int s1 = c4.y + s2;
      int s0 = c4.x + s1;
      int suf = s0;
      for (int off = 1; off < 64; off <<= 1) {
        int t = __shfl_down(suf, off, 64);
        if (lane + off < 64) suf += t;
      }
      int above = suf - s0;
      int S0 = above + s0, S1 = above + s1, S2 = above + s2, S3 = above + s3v;
      int S4 = above;
      if (S3 >= Krem && S4 < Krem) { sdig = 4 * lane + 3; scum = S4; }
      else if (S2 >= Krem && S3 < Krem) { sdig = 4 * lane + 2; scum = S3; }
      else if (S1 >= Krem && S2 < Krem) { sdig = 4 * lane + 1; scum = S2; }
      else if (S0 >= Krem && S1 < Krem) { sdig = 4 * lane + 0; scum = S1; }
    }
    __syncthreads();
    pfx |= ((unsigned)sdig) << sh;
    Krem -= scum;
  }
  float tau = __uint_as_float(pfx);

  float sum = 0.0f;
  int cgt = 0;
  for (int i = tid; i < P / 4; i += TPB2) {
    float4 v = row4[i];
    if (v.x > tau) { sum += v.x; cgt++; }
    if (v.y > tau) { sum += v.y; cgt++; }
    if (v.z > tau) { sum += v.z; cgt++; }
    if (v.w > tau) { sum += v.w; cgt++; }
  }
  for (int off = 32; off >= 1; off >>= 1) {
    sum += __shfl_down(sum, off, 64);
    cgt += __shfl_down(cgt, off, 64);
  }
  if (lane == 0) { u.s3.rsum[wid] = sum; u.s3.rcnt[wid] = cgt; }
  __syncthreads();
  if (tid == 0) {
    float stot = u.s3.rsum[0] + u.s3.rsum[1] + u.s3.rsum[2] + u.s3.rsum[3];
    int ctot = u.s3.rcnt[0] + u.s3.rcnt[1] + u.s3.rcnt[2] + u.s3.rcnt[3];
    float hard = stot + (float)(K - ctot) * tau;
    ST_AGENT(&imgres[b * 4 + 0], sLoc);
    ST_AGENT(&imgres[b * 4 + 1], sCe);
    ST_AGENT(&imgres[b * 4 + 2], hard);
    ST_AGENT(&imgres[b * 4 + 3], sNp);
    asm volatile("s_waitcnt vmcnt(0)" ::: "memory");  // imgres at L3
    int prev = __hip_atomic_fetch_add(done, 1, __ATOMIC_RELAXED,
                                      __HIP_MEMORY_SCOPE_AGENT);
    sLastImg = (prev == B - 1) ? 1 : 0;
  }
  __syncthreads();
  if (sLastImg) {
    __builtin_amdgcn_fence(__ATOMIC_ACQUIRE, "agent");  // invalidate, no wb
    float l = 0.0f, c = 0.0f, h = 0.0f, n = 0.0f;
    if (tid < B) {
      l = atomicAdd(&imgres[tid * 4 + 0], 0.0f);
      c = atomicAdd(&imgres[tid * 4 + 1], 0.0f);
      h = atomicAdd(&imgres[tid * 4 + 2], 0.0f);
      n = atomicAdd(&imgres[tid * 4 + 3], 0.0f);
    }
    for (int off = 32; off >= 1; off >>= 1) {
      l += __shfl_down(l, off, 64);
      c += __shfl_down(c, off, 64);
      h += __shfl_down(h, off, 64);
      n += __shfl_down(n, off, 64);
    }
    if (lane == 0) { u.s3.rl[wid] = l; u.s3.rc[wid] = c; u.s3.rh[wid] = h; u.s3.rn[wid] = n; }
    __syncthreads();
    if (tid == 0) {
      float L = 0, Cc = 0, H = 0, N = 0;
#pragma unroll
      for (int w = 0; w < 4; w++) {
        L += u.s3.rl[w]; Cc += u.s3.rc[w]; H += u.s3.rh[w]; N += u.s3.rn[w];
      }
      float loc = ALPHA * L / (N * 4.0f);
      float conf = (H + Cc) / N;
      out[0] = conf + loc;
      out[1] = loc;
      out[2] = conf;
    }
  }
}

extern "C" void kernel_launch(void* const* d_in, const int* in_sizes, int n_in,
                              void* d_out, int out_size, void* d_ws, size_t ws_size,
                              hipStream_t stream) {
  (void)in_sizes; (void)n_in; (void)out_size; (void)ws_size;
  const float* pred_loc = (const float*)d_in[0];
  const float* pred_cls = (const float*)d_in[1];
  const float* b_boxes = (const float*)d_in[2];
  const int* b_labels = (const int*)d_in[3];
  const float* priors = (const float*)d_in[4];
  float* out = (float*)d_out;

  int* done = (int*)d_ws;
  int* imgcnt = (int*)d_ws + 8;
  float* ploc = (float*)d_ws + 8 + B;
  float* pce = ploc + B * NB2;
  int* pnp = (int*)(pce + B * NB2);
  float* imgres = (float*)(pnp + B * NB2);
  float* pI = imgres + B * 4;
  float* pU = pI + B * M * CH;
  int* pidx = (int*)(pU + B * M * CH);
  float* confneg = (float*)(pidx + B * M * CH);  // 16B-aligned

  k1_partial<<<B * CH, 256, 0, stream>>>(b_boxes, priors, pI, pU, pidx, done, imgcnt);
  dim3 g2(NB2, B);
  k23_fused<<<g2, TPB2, 0, stream>>>(pred_loc, pred_cls, b_boxes, b_labels,
                                     priors, pI, pU, pidx, ploc, pce, pnp,
                                     confneg, imgcnt, imgres, done, out);
}

// Round 4
// 275.007 us; speedup vs baseline: 1.8349x; 1.0088x over previous
//
#include <hip/hip_runtime.h>
#include <math.h>

#define B 128
#define M 32
#define P 8732
#define C 21
#define ALPHA 10.0f
#define TPB2 256
#define PPB 256          // priors per block in fused kernel (1 per lane, 64 per wave)
#define NB2 35           // ceil(P / PPB)
#define CH 8             // k1 prior chunks
#define CS 1092          // ceil(P / CH)
#define NR4 9            // ceil((P/4) / TPB2) float4 regs per thread in phase B

// direct global->LDS DMA, 16 B/lane, wave-uniform LDS base + lane*16 scatter
#define GLD16(g, l)                                                   \
  __builtin_amdgcn_global_load_lds(                                   \
      (__attribute__((address_space(1))) void*)(g),                   \
      (__attribute__((address_space(3))) void*)(l), 16, 0, 0)

// agent-scope relaxed store: lowers to an sc1 write that reaches the MALL
// (cross-XCD coherence point) without any buffer_wbl2 L2 flush.
#define ST_AGENT(p, v) \
  __hip_atomic_store((p), (v), __ATOMIC_RELAXED, __HIP_MEMORY_SCOPE_AGENT)

// ---------------- k1a: per-chunk best prior per object (partials) -----------
__global__ __launch_bounds__(256) void k1_partial(
    const float* __restrict__ b_boxes, const float* __restrict__ priors,
    float* __restrict__ pI, float* __restrict__ pU, int* __restrict__ pidx,
    int* __restrict__ done, int* __restrict__ imgcnt) {
  if (blockIdx.x == 0) {
    if (threadIdx.x == 0) *done = 0;
    if (threadIdx.x < B) imgcnt[threadIdx.x] = 0;  // per-image block counters
  }
  int b = blockIdx.x >> 3;
  int ch = blockIdx.x & 7;
  int wid = threadIdx.x >> 6;
  int lane = threadIdx.x & 63;
  int obase = wid * 8;

  float ox1[8], oy1[8], ox2[8], oy2[8], oarea[8], bI[8], bU[8];
  int bidx[8];
#pragma unroll
  for (int k = 0; k < 8; k++) {
    float4 bx = ((const float4*)b_boxes)[(size_t)b * M + obase + k];
    ox1[k] = bx.x; oy1[k] = bx.y; ox2[k] = bx.z; oy2[k] = bx.w;
    oarea[k] = (bx.z - bx.x) * (bx.w - bx.y);
    bI[k] = -1.0f; bU[k] = 1.0f; bidx[k] = P;
  }

  int pend = (ch + 1) * CS;
  if (pend > P) pend = P;
#pragma unroll 2
  for (int p = ch * CS + lane; p < pend; p += 64) {
    float4 pr = ((const float4*)priors)[p];
    float pw2 = pr.z * 0.5f, ph2 = pr.w * 0.5f;
    float px1 = pr.x - pw2, py1 = pr.y - ph2;
    float px2 = pr.x + pw2, py2 = pr.y + ph2;
    float areaP = pr.z * pr.w;
#pragma unroll
    for (int k = 0; k < 8; k++) {
      float iw = fminf(ox2[k], px2) - fmaxf(ox1[k], px1);
      float ih = fminf(oy2[k], py2) - fmaxf(oy1[k], py1);
      iw = fmaxf(iw, 0.0f);
      ih = fmaxf(ih, 0.0f);
      float inter = iw * ih;
      float uni = oarea[k] + areaP - inter;
      if (inter * bU[k] > bI[k] * uni) { bI[k] = inter; bU[k] = uni; bidx[k] = p; }
    }
  }
  for (int off = 32; off >= 1; off >>= 1) {
#pragma unroll
    for (int k = 0; k < 8; k++) {
      float oI = __shfl_xor(bI[k], off, 64);
      float oU = __shfl_xor(bU[k], off, 64);
      int oi = __shfl_xor(bidx[k], off, 64);
      float l = oI * bU[k], r = bI[k] * oU;
      if (l > r || (l == r && oi < bidx[k])) { bI[k] = oI; bU[k] = oU; bidx[k] = oi; }
    }
  }
  if (lane == 0) {
#pragma unroll
    for (int k = 0; k < 8; k++) {
      int idx = ((size_t)b * M + obase + k) * CH + ch;
      pI[idx] = bI[k]; pU[idx] = bU[k]; pidx[idx] = bidx[k];
    }
  }
}

// ---------------- fused k2+k3: per-prior match + CE, then per-image ---------
// hard-negative top-K done by the LAST block of each image (done-counter
// pattern). Cross-XCD handoff: sc1 stores + vmcnt drain + relaxed agent
// atomics; reader does acquire-only invalidate (no wbl2).
// Phase B register-stages the confneg row ONCE (9 float4/thread) and runs
// all radix passes + final sum from registers — the R3 version's 5 global
// re-sweeps at MALL latency were the ~100 us low-occupancy tail.
__global__ __launch_bounds__(TPB2) void k23_fused(
    const float* __restrict__ pred_loc, const float* __restrict__ pred_cls,
    const float* __restrict__ b_boxes, const int* __restrict__ b_labels,
    const float* __restrict__ priors,
    const float* __restrict__ pI, const float* __restrict__ pU,
    const int* __restrict__ pidx,
    float* __restrict__ ploc, float* __restrict__ pce, int* __restrict__ pnp,
    float* __restrict__ confneg, int* __restrict__ imgcnt,
    float* __restrict__ imgres, int* __restrict__ done,
    float* __restrict__ out) {
  int b = blockIdx.y;
  int p0 = blockIdx.x * PPB;
  int tid = threadIdx.x;
  int wid = tid >> 6;
  int lane = tid & 63;

  __shared__ __align__(16) union SU {
    struct {
      float cls[4][64 * C];  // 21504 B (wave-private class tiles)
      float4 box[M];
      float area[M];
      int lab[M];
      int obj[M];
      int inv[PPB];
    } a;
    struct {               // phase B (select) scratch — reuses phase-A LDS
      int histw[4 * 256];  // per-wave radix histograms
      int cnt[256];
      float rsum[4];
      int rcnt[4];
      float rl[4], rc[4], rh[4], rn[4];
    } s3;
  } u;
  __shared__ float rloc[4], rce[4];
  __shared__ int rnp[4];
  __shared__ int sdig, scum, sLastBlk, sLastImg, sK;
  __shared__ float sLoc, sCe, sNp;

  // ---------------- phase A: identical structure to the 214us k2 ------------
  {
    int wp0 = p0 + wid * 64;
    int nv = P - wp0;
    nv = nv < 0 ? 0 : (nv > 64 ? 64 : nv);
    int nf4 = (nv * C) >> 2;  // 336 (full), 147 (tail), or 0
    const float4* src = (const float4*)(pred_cls + ((size_t)b * P + wp0) * C);
#pragma unroll
    for (int k = 0; k < 6; k++) {
      int idx = (k << 6) + lane;
      if (idx < nf4) GLD16(src + idx, &u.a.cls[wid][k << 8]);
    }
  }

  u.a.inv[tid] = 0x7fffffff;
  if (tid < M) {
    int m = tid;
    float4 bx = ((const float4*)b_boxes)[b * M + m];
    u.a.box[m] = bx;
    u.a.area[m] = (bx.z - bx.x) * (bx.w - bx.y);
    u.a.lab[m] = b_labels[b * M + m];
    // fused k1_reduce: fold 8 chunk partials for object m of image b
    int o = b * M + m;
    float cI = pI[o * CH], cU = pU[o * CH];
    int ci = pidx[o * CH];
#pragma unroll
    for (int ch = 1; ch < CH; ch++) {
      float nI = pI[o * CH + ch], nU = pU[o * CH + ch];
      int ni = pidx[o * CH + ch];
      if (nI * cU > cI * nU) { cI = nI; cU = nU; ci = ni; }
    }
    u.a.obj[m] = ci;
  }
  __syncthreads();
  if (tid < M) {
    int t = u.a.obj[tid] - p0;
    if (t >= 0 && t < PPB) atomicMin(&u.a.inv[t], tid);
  }
  __syncthreads();  // drains the global_load_lds vmcnt + orders inv

  float locpart = 0.0f, cepospart = 0.0f;
  int npos = 0;
  int p = p0 + tid;
  if (p < P) {
    float4 pr = ((const float4*)priors)[p];
    float pw2 = pr.z * 0.5f, ph2 = pr.w * 0.5f;
    float px1 = pr.x - pw2, py1 = pr.y - ph2;
    float px2 = pr.x + pw2, py2 = pr.y + ph2;
    float areaP = pr.z * pr.w;
    float bI = -1.0f, bU = 1.0f;
    int bm = 0;
    for (int m = 0; m < M; m++) {
      float4 bx = u.a.box[m];  // one ds_read_b128 broadcast per object
      float iw = fminf(bx.z, px2) - fmaxf(bx.x, px1);
      float ih = fminf(bx.w, py2) - fmaxf(bx.y, py1);
      iw = fmaxf(iw, 0.0f);
      ih = fmaxf(ih, 0.0f);
      float inter = iw * ih;
      float uni = u.a.area[m] + areaP - inter;
      if (inter * bU > bI * uni) { bI = inter; bU = uni; bm = m; }
    }
    // forced best-prior override (first-max semantics preserved)
    int fm = u.a.inv[tid];
    if (fm != 0x7fffffff) {
      if (!((bI == bU) && (bm < fm))) { bI = 1.0f; bU = 1.0f; bm = fm; }
    }
    bool pos = (2.0f * bI >= bU);  // iou >= 0.5, division-free
    int wAny = __any((int)pos);

    if (wAny) {  // wave-uniform positive path: loc load + encode + L1 loss
      float4 pl = ((const float4*)pred_loc)[(size_t)b * P + p];
      float4 bx = u.a.box[bm];
      float cx = (bx.x + bx.z) * 0.5f, cy = (bx.y + bx.w) * 0.5f;
      float w = bx.z - bx.x, h = bx.w - bx.y;
      float rz = __builtin_amdgcn_rcpf(pr.z);
      float rw = __builtin_amdgcn_rcpf(pr.w);
      float g0 = (cx - pr.x) * 10.0f * rz;
      float g1 = (cy - pr.y) * 10.0f * rw;
      float g2 = __logf(w * rz) * 5.0f;
      float g3 = __logf(h * rw) * 5.0f;
      if (pos) {
        locpart = fabsf(pl.x - g0) + fabsf(pl.y - g1) +
                  fabsf(pl.z - g2) + fabsf(pl.w - g3);
        npos = 1;
      }
    }

    // CE from LDS (unstabilized logsumexp; verified absmax 0.0 since R9)
    const float* cptr = &u.a.cls[wid][lane * C];
    int cls = pos ? u.a.lab[bm] : 0;
    float se = 0.0f, vc = 0.0f;
#pragma unroll
    for (int c = 0; c < C; c++) {
      float x = cptr[c];
      se += __expf(x);
      if (c == cls) vc = x;  // predicated select, constant index
    }
    float ce = __logf(se) - vc;
    ST_AGENT(&confneg[(size_t)b * P + p], pos ? 0.0f : ce);  // sc1: reaches L3
    cepospart = pos ? ce : 0.0f;
  }

  for (int off = 32; off >= 1; off >>= 1) {
    locpart += __shfl_down(locpart, off, 64);
    cepospart += __shfl_down(cepospart, off, 64);
    npos += __shfl_down(npos, off, 64);
  }
  if (lane == 0) { rloc[wid] = locpart; rce[wid] = cepospart; rnp[wid] = npos; }
  // every wave drains its own sc1 confneg stores to the coherence point
  asm volatile("s_waitcnt vmcnt(0)" ::: "memory");
  __syncthreads();
  if (tid == 0) {
    int f = b * NB2 + blockIdx.x;
    ST_AGENT(&ploc[f], rloc[0] + rloc[1] + rloc[2] + rloc[3]);
    ST_AGENT(&pce[f], rce[0] + rce[1] + rce[2] + rce[3]);
    ST_AGENT(&pnp[f], rnp[0] + rnp[1] + rnp[2] + rnp[3]);
    asm volatile("s_waitcnt vmcnt(0)" ::: "memory");  // partials at L3
    int prev = __hip_atomic_fetch_add(&imgcnt[b], 1, __ATOMIC_RELAXED,
                                      __HIP_MEMORY_SCOPE_AGENT);
    sLastBlk = (prev == NB2 - 1) ? 1 : 0;
  }
  __syncthreads();
  if (!sLastBlk) return;
  // acquire-only: buffer_inv (L1+L2 invalidate), NO writeback
  __builtin_amdgcn_fence(__ATOMIC_ACQUIRE, "agent");

  // ---------------- phase B: this image's hard-negative top-K ---------------
  // register-stage the whole row ONCE: P/4 = 2183 float4, 9 per thread.
  // Issue the loads first so they overlap the wave-0 partial reduce below.
  float4 rv[NR4];
  {
    const float4* row4 = (const float4*)(confneg + (size_t)b * P);
#pragma unroll
    for (int k = 0; k < NR4; k++) {
      int i = (k << 8) + tid;
      if (i < P / 4) rv[k] = row4[i];
    }
  }

  if (wid == 0) {  // reduce this image's 35 per-block partials
    float lp = 0.0f, cp = 0.0f;
    int np = 0;
    if (lane < NB2) {
      int f = b * NB2 + lane;
      lp = ploc[f]; cp = pce[f]; np = pnp[f];
    }
    for (int off = 32; off >= 1; off >>= 1) {
      lp += __shfl_down(lp, off, 64);
      cp += __shfl_down(cp, off, 64);
      np += __shfl_down(np, off, 64);
    }
    if (lane == 0) {
      int K = np * 3;
      if (K > P) K = P;
      sK = K; sLoc = lp; sCe = cp; sNp = (float)np;
    }
  }
  __syncthreads();

  int K = sK;
  unsigned pfx = 0;
  int Krem = K;
#pragma unroll
  for (int pass = 3; pass >= 0; --pass) {
    int sh = pass * 8;
    for (int i = tid; i < 4 * 256; i += TPB2) u.s3.histw[i] = 0;
    __syncthreads();
    unsigned himask = (pass == 3) ? 0u : (0xFFFFFFFFu << (sh + 8));
    int* myh = &u.s3.histw[wid * 256];
#pragma unroll
    for (int k = 0; k < NR4; k++) {
      int i = (k << 8) + tid;
      if (i < P / 4) {
        unsigned u0 = __float_as_uint(rv[k].x), u1 = __float_as_uint(rv[k].y);
        unsigned u2 = __float_as_uint(rv[k].z), u3 = __float_as_uint(rv[k].w);
        if ((u0 & himask) == pfx) atomicAdd(&myh[(u0 >> sh) & 255], 1);
        if ((u1 & himask) == pfx) atomicAdd(&myh[(u1 >> sh) & 255], 1);
        if ((u2 & himask) == pfx) atomicAdd(&myh[(u2 >> sh) & 255], 1);
        if ((u3 & himask) == pfx) atomicAdd(&myh[(u3 >> sh) & 255], 1);
      }
    }
    __syncthreads();
    {
      int c = u.s3.histw[tid] + u.s3.histw[256 + tid] +
              u.s3.histw[512 + tid] + u.s3.histw[768 + tid];
      u.s3.cnt[tid] = c;
    }
    __syncthreads();
    if (wid == 0) {
      int4 c4 = ((const int4*)u.s3.cnt)[lane];
      int s3v = c4.w;
      int s2 = c4.z + s3v;
      int s1 = c4.y + s2;
      int s0 = c4.x + s1;
      int suf = s0;
      for (int off = 1; off < 64; off <<= 1) {
        int t = __shfl_down(suf, off, 64);
        if (lane + off < 64) suf += t;
      }
      int above = suf - s0;
      int S0 = above + s0, S1 = above + s1, S2 = above + s2, S3 = above + s3v;
      int S4 = above;
      if (S3 >= Krem && S4 < Krem) { sdig = 4 * lane + 3; scum = S4; }
      else if (S2 >= Krem && S3 < Krem) { sdig = 4 * lane + 2; scum = S3; }
      else if (S1 >= Krem && S2 < Krem) { sdig = 4 * lane + 1; scum = S2; }
      else if (S0 >= Krem && S1 < Krem) { sdig = 4 * lane + 0; scum = S1; }
    }
    __syncthreads();
    pfx |= ((unsigned)sdig) << sh;
    Krem -= scum;
  }
  float tau = __uint_as_float(pfx);

  float sum = 0.0f;
  int cgt = 0;
#pragma unroll
  for (int k = 0; k < NR4; k++) {
    int i = (k << 8) + tid;
    if (i < P / 4) {
      if (rv[k].x > tau) { sum += rv[k].x; cgt++; }
      if (rv[k].y > tau) { sum += rv[k].y; cgt++; }
      if (rv[k].z > tau) { sum += rv[k].z; cgt++; }
      if (rv[k].w > tau) { sum += rv[k].w; cgt++; }
    }
  }
  for (int off = 32; off >= 1; off >>= 1) {
    sum += __shfl_down(sum, off, 64);
    cgt += __shfl_down(cgt, off, 64);
  }
  if (lane == 0) { u.s3.rsum[wid] = sum; u.s3.rcnt[wid] = cgt; }
  __syncthreads();
  if (tid == 0) {
    float stot = u.s3.rsum[0] + u.s3.rsum[1] + u.s3.rsum[2] + u.s3.rsum[3];
    int ctot = u.s3.rcnt[0] + u.s3.rcnt[1] + u.s3.rcnt[2] + u.s3.rcnt[3];
    float hard = stot + (float)(K - ctot) * tau;
    ST_AGENT(&imgres[b * 4 + 0], sLoc);
    ST_AGENT(&imgres[b * 4 + 1], sCe);
    ST_AGENT(&imgres[b * 4 + 2], hard);
    ST_AGENT(&imgres[b * 4 + 3], sNp);
    asm volatile("s_waitcnt vmcnt(0)" ::: "memory");  // imgres at L3
    int prev = __hip_atomic_fetch_add(done, 1, __ATOMIC_RELAXED,
                                      __HIP_MEMORY_SCOPE_AGENT);
    sLastImg = (prev == B - 1) ? 1 : 0;
  }
  __syncthreads();
  if (sLastImg) {
    __builtin_amdgcn_fence(__ATOMIC_ACQUIRE, "agent");  // invalidate, no wb
    float l = 0.0f, c = 0.0f, h = 0.0f, n = 0.0f;
    if (tid < B) {
      l = atomicAdd(&imgres[tid * 4 + 0], 0.0f);
      c = atomicAdd(&imgres[tid * 4 + 1], 0.0f);
      h = atomicAdd(&imgres[tid * 4 + 2], 0.0f);
      n = atomicAdd(&imgres[tid * 4 + 3], 0.0f);
    }
    for (int off = 32; off >= 1; off >>= 1) {
      l += __shfl_down(l, off, 64);
      c += __shfl_down(c, off, 64);
      h += __shfl_down(h, off, 64);
      n += __shfl_down(n, off, 64);
    }
    if (lane == 0) { u.s3.rl[wid] = l; u.s3.rc[wid] = c; u.s3.rh[wid] = h; u.s3.rn[wid] = n; }
    __syncthreads();
    if (tid == 0) {
      float L = 0, Cc = 0, H = 0, N = 0;
#pragma unroll
      for (int w = 0; w < 4; w++) {
        L += u.s3.rl[w]; Cc += u.s3.rc[w]; H += u.s3.rh[w]; N += u.s3.rn[w];
      }
      float loc = ALPHA * L / (N * 4.0f);
      float conf = (H + Cc) / N;
      out[0] = conf + loc;
      out[1] = loc;
      out[2] = conf;
    }
  }
}

extern "C" void kernel_launch(void* const* d_in, const int* in_sizes, int n_in,
                              void* d_out, int out_size, void* d_ws, size_t ws_size,
                              hipStream_t stream) {
  (void)in_sizes; (void)n_in; (void)out_size; (void)ws_size;
  const float* pred_loc = (const float*)d_in[0];
  const float* pred_cls = (const float*)d_in[1];
  const float* b_boxes = (const float*)d_in[2];
  const int* b_labels = (const int*)d_in[3];
  const float* priors = (const float*)d_in[4];
  float* out = (float*)d_out;

  int* done = (int*)d_ws;
  int* imgcnt = (int*)d_ws + 8;
  float* ploc = (float*)d_ws + 8 + B;
  float* pce = ploc + B * NB2;
  int* pnp = (int*)(pce + B * NB2);
  float* imgres = (float*)(pnp + B * NB2);
  float* pI = imgres + B * 4;
  float* pU = pI + B * M * CH;
  int* pidx = (int*)(pU + B * M * CH);
  float* confneg = (float*)(pidx + B * M * CH);  // 16B-aligned

  k1_partial<<<B * CH, 256, 0, stream>>>(b_boxes, priors, pI, pU, pidx, done, imgcnt);
  dim3 g2(NB2, B);
  k23_fused<<<g2, TPB2, 0, stream>>>(pred_loc, pred_cls, b_boxes, b_labels,
                                     priors, pI, pU, pidx, ploc, pce, pnp,
                                     confneg, imgcnt, imgres, done, out);
}